// Round 7
// baseline (493.005 us; speedup 1.0000x reference)
//
#include <hip/hip_runtime.h>
#include <hip/hip_cooperative_groups.h>

namespace cg = cooperative_groups;

typedef _Float16 half2v __attribute__((ext_vector_type(2)));
typedef _Float16 half4v __attribute__((ext_vector_type(4)));
typedef _Float16 half8  __attribute__((ext_vector_type(8)));
typedef float    floatx4 __attribute__((ext_vector_type(4)));

// ---------------- ws layout ----------------
// [0, 25600000)           tab: normalized fp16 table, 100000x128 (slice s = rows [s*12500,(s+1)*12500))
// [25600000, 25690112)    pooled: [128][176] fp32
#define TAB_OFF   0
#define POOL_OFF  25600000
#define WS_NEEDED 25690112

// ---- fused cooperative kernel: normalize -> grid.sync -> gather/MFMA/RBF -> grid.sync -> final ----
__global__ __launch_bounds__(256) void knrm_fused(
    const int*   __restrict__ queries,    // 128 x 16
    const int*   __restrict__ documents,  // 128 x 2048
    const float* __restrict__ emb,        // 100000 x 128
    const float* __restrict__ W,          // 11
    const float* __restrict__ bias,       // 1
    _Float16*    __restrict__ tab,        // normalized fp16 table
    float*       __restrict__ pooled,     // [128][176]
    float*       __restrict__ out)        // 128
{
    __shared__ __align__(16) _Float16 Qs[16][136];
    __shared__ __align__(16) _Float16 Ds[4][16][136];
    __shared__ int   list_s[2048];
    __shared__ int   cnt_s;
    __shared__ float pooled_s[176];

    const int g    = blockIdx.x;      // 1024 blocks
    const int tid  = threadIdx.x;
    const int lane = tid & 63;
    const int wave = tid >> 6;
    const int s    = g & 7;           // slice; == XCD under round-robin dispatch (perf heuristic only)
    const int bb   = g >> 3;          // batch index (phase 2/3) & row-interleave id (phase 1)

    // ---------------- phase 1: build normalized table slice + own-batch Q in LDS ----------------
    if (g < 88) pooled[g * 256 + tid] = 0.0f;

    // 1a: this block normalizes rows s*12500 + t*128 + bb (one 512B row per wave-iter)
    for (int t = wave; t < 98; t += 4) {
        const int i = t * 128 + bb;
        if (i < 12500) {
            const int row = s * 12500 + i;
            const float x = __builtin_nontemporal_load(emb + (size_t)row * 128 + lane * 2);
            const float y = __builtin_nontemporal_load(emb + (size_t)row * 128 + lane * 2 + 1);
            float ns = x * x + y * y;
            ns += __shfl_xor(ns, 1);  ns += __shfl_xor(ns, 2);
            ns += __shfl_xor(ns, 4);  ns += __shfl_xor(ns, 8);
            ns += __shfl_xor(ns, 16); ns += __shfl_xor(ns, 32);
            const float sc = (ns > 0.0f) ? __frsqrt_rn(ns) : 0.0f;
            half2v h; h[0] = (_Float16)(x * sc); h[1] = (_Float16)(y * sc);
            *((half2v*)(tab + (size_t)row * 128) + lane) = h;   // cached store -> stays in local L2
        }
    }

    // 1b: normalize this batch's 16 query rows straight into LDS (no cross-block dependency)
    for (int q = wave; q < 16; q += 4) {
        const int row = queries[bb * 16 + q];
        const float x = emb[(size_t)row * 128 + lane * 2];
        const float y = emb[(size_t)row * 128 + lane * 2 + 1];
        float ns = x * x + y * y;
        ns += __shfl_xor(ns, 1);  ns += __shfl_xor(ns, 2);
        ns += __shfl_xor(ns, 4);  ns += __shfl_xor(ns, 8);
        ns += __shfl_xor(ns, 16); ns += __shfl_xor(ns, 32);
        const float sc = (ns > 0.0f) ? __frsqrt_rn(ns) : 0.0f;
        Qs[q][lane * 2]     = (_Float16)(x * sc);
        Qs[q][lane * 2 + 1] = (_Float16)(y * sc);
    }

    if (tid == 0) cnt_s = 0;
    if (tid < 176) pooled_s[tid] = 0.0f;

    __threadfence();
    cg::this_grid().sync();   // tab visible device-wide; same-XCD readers hit dirty L2

    // ---------------- phase 2: compact in-slice tokens, gather XCD-local, MFMA, RBF ----------------
    const unsigned lo = (unsigned)(s * 12500);
    for (int r = 0; r < 8; ++r) {
        const int idx = documents[bb * 2048 + r * 256 + tid];
        const bool hit = ((unsigned)idx - lo) < 12500u;
        const unsigned long long mask = __ballot(hit);
        const int prefix = __popcll(mask & ((1ull << lane) - 1ull));
        int base = 0;
        if (lane == 0 && mask) base = atomicAdd(&cnt_s, __popcll(mask));
        base = __shfl(base, 0);
        if (hit) list_s[base + prefix] = idx;
    }
    __syncthreads();
    const int cnt = cnt_s;
    const int M   = (cnt + 15) >> 4;

    const int col  = lane & 15;   // MFMA: token / A row m
    const int quad = lane >> 4;   // MFMA: k-octet / C row group

    half8 afrag[4];
#pragma unroll
    for (int c = 0; c < 4; ++c)
        afrag[c] = *(const half8*)&Qs[col][c * 32 + quad * 8];

    float pr[4][11];
#pragma unroll
    for (int r = 0; r < 4; ++r)
#pragma unroll
        for (int k = 0; k < 11; ++k) pr[r][k] = 0.0f;

    const int rsel  = lane >> 4;   // 4 rows per gather instr
    const int chunk = lane & 15;   // 16B chunk within row

    for (int c = wave; c < M; c += 4) {
#pragma unroll
        for (int j = 0; j < 4; ++j) {
            const int p   = c * 16 + j * 4 + rsel;
            const int idx = (p < cnt) ? list_s[p] : (int)lo;   // pad -> in-slice row (masked below)
            *(uint4*)&Ds[wave][j * 4 + rsel][chunk * 8] =
                *(const uint4*)(tab + (size_t)idx * 128 + chunk * 8);
        }
        floatx4 acc = {0.0f, 0.0f, 0.0f, 0.0f};
#pragma unroll
        for (int cc = 0; cc < 4; ++cc) {
            half8 bf = *(const half8*)&Ds[wave][col][cc * 32 + quad * 8];
            acc = __builtin_amdgcn_mfma_f32_16x16x32_f16(afrag[cc], bf, acc, 0, 0, 0);
        }
        if (c * 16 + col < cnt) {
#pragma unroll
            for (int r = 0; r < 4; ++r) {
                const float sim = acc[r];
#pragma unroll
                for (int k = 0; k < 11; ++k) {
                    const float tt = sim - (-1.0f + 0.2f * (float)k);
                    pr[r][k] += __builtin_amdgcn_exp2f(tt * tt * -72.13475204444817f);
                }
            }
        }
    }

#pragma unroll
    for (int r = 0; r < 4; ++r)
#pragma unroll
        for (int k = 0; k < 11; ++k)
            atomicAdd(&pooled_s[(quad * 4 + r) * 11 + k], pr[r][k]);
    __syncthreads();
    if (tid < 176) atomicAdd(&pooled[bb * 176 + tid], pooled_s[tid]);

    __threadfence();
    cg::this_grid().sync();   // pooled complete, device-visible

    // ---------------- phase 3: final log/dot/sigmoid (blocks 0..31, one wave per batch) ----------------
    if (g < 32) {
        const int batch = g * 4 + wave;
        const float* pb = pooled + (size_t)batch * 176;
        float acc = 0.0f;
#pragma unroll
        for (int i = 0; i < 3; ++i) {
            const int f = lane + i * 64;
            if (f < 176)
                acc += __builtin_amdgcn_logf(pb[f]) * W[f % 11];   // log2
        }
        acc += __shfl_xor(acc, 1);  acc += __shfl_xor(acc, 2);
        acc += __shfl_xor(acc, 4);  acc += __shfl_xor(acc, 8);
        acc += __shfl_xor(acc, 16); acc += __shfl_xor(acc, 32);
        if (lane == 0) {
            const float t = acc * 0.69314718055994531f + bias[0];
            out[batch] = __builtin_amdgcn_rcpf(1.0f + __builtin_amdgcn_exp2f(t * -1.4426950408889634f));
        }
    }
}

// ================= fallback (non-cooperative 3-kernel path, R6 structure) =================
__global__ __launch_bounds__(256) void knrm_prep_fb(
    const float* __restrict__ emb, const int* __restrict__ queries,
    _Float16* __restrict__ tab, _Float16* __restrict__ qtab, float* __restrict__ pooled)
{
    const int g = blockIdx.x, tid = threadIdx.x;
    if (g < 88) pooled[g * 256 + tid] = 0.0f;
    const int lane = tid & 63, wave = tid >> 6;
    if (g < 2048) {
        const int s = g & 7, wid = (g >> 3) * 4 + wave;
        for (int i = wid; i < 12500; i += 1024) {
            const int row = s * 12500 + i;
            const float x = __builtin_nontemporal_load(emb + (size_t)row * 128 + lane * 2);
            const float y = __builtin_nontemporal_load(emb + (size_t)row * 128 + lane * 2 + 1);
            float ns = x * x + y * y;
            ns += __shfl_xor(ns, 1);  ns += __shfl_xor(ns, 2);
            ns += __shfl_xor(ns, 4);  ns += __shfl_xor(ns, 8);
            ns += __shfl_xor(ns, 16); ns += __shfl_xor(ns, 32);
            const float sc = (ns > 0.0f) ? __frsqrt_rn(ns) : 0.0f;
            half2v h; h[0] = (_Float16)(x * sc); h[1] = (_Float16)(y * sc);
            *((half2v*)(tab + (size_t)row * 128) + lane) = h;
        }
    } else {
        const int b = g - 2048;
        for (int q = wave; q < 16; q += 4) {
            const int row = queries[b * 16 + q];
            const float x = emb[(size_t)row * 128 + lane * 2];
            const float y = emb[(size_t)row * 128 + lane * 2 + 1];
            float ns = x * x + y * y;
            ns += __shfl_xor(ns, 1);  ns += __shfl_xor(ns, 2);
            ns += __shfl_xor(ns, 4);  ns += __shfl_xor(ns, 8);
            ns += __shfl_xor(ns, 16); ns += __shfl_xor(ns, 32);
            const float sc = (ns > 0.0f) ? __frsqrt_rn(ns) : 0.0f;
            half2v h; h[0] = (_Float16)(x * sc); h[1] = (_Float16)(y * sc);
            *((half2v*)(qtab + ((size_t)b * 16 + q) * 128) + lane) = h;
        }
    }
}

__global__ __launch_bounds__(256) void knrm_main_fb(
    const int* __restrict__ documents, const _Float16* __restrict__ tab,
    const _Float16* __restrict__ qtab, float* __restrict__ pooled)
{
    __shared__ __align__(16) _Float16 Qs[16][136];
    __shared__ __align__(16) _Float16 Ds[4][16][136];
    __shared__ int   list_s[2048];
    __shared__ int   cnt_s;
    __shared__ float pooled_s[176];

    const int tid = threadIdx.x;
    const int s   = blockIdx.x & 7;
    const int b   = blockIdx.x >> 3;

    if (tid == 0) cnt_s = 0;
    if (tid < 176) pooled_s[tid] = 0.0f;
    {
        const int row = tid >> 4, chunk = tid & 15;
        *(uint4*)&Qs[row][chunk * 8] =
            *(const uint4*)(qtab + ((size_t)b * 16 + row) * 128 + chunk * 8);
    }
    __syncthreads();

    const int lane = tid & 63;
    const int wave = tid >> 6;

    const unsigned lo = (unsigned)(s * 12500);
    for (int r = 0; r < 8; ++r) {
        const int idx = documents[b * 2048 + r * 256 + tid];
        const bool hit = ((unsigned)idx - lo) < 12500u;
        const unsigned long long mask = __ballot(hit);
        const int prefix = __popcll(mask & ((1ull << lane) - 1ull));
        int base = 0;
        if (lane == 0 && mask) base = atomicAdd(&cnt_s, __popcll(mask));
        base = __shfl(base, 0);
        if (hit) list_s[base + prefix] = idx;
    }
    __syncthreads();
    const int cnt = cnt_s;
    const int M   = (cnt + 15) >> 4;

    const int col  = lane & 15;
    const int quad = lane >> 4;

    half8 afrag[4];
#pragma unroll
    for (int c = 0; c < 4; ++c)
        afrag[c] = *(const half8*)&Qs[col][c * 32 + quad * 8];

    float pr[4][11];
#pragma unroll
    for (int r = 0; r < 4; ++r)
#pragma unroll
        for (int k = 0; k < 11; ++k) pr[r][k] = 0.0f;

    const int rsel  = lane >> 4;
    const int chunk = lane & 15;

    for (int c = wave; c < M; c += 4) {
#pragma unroll
        for (int j = 0; j < 4; ++j) {
            const int p   = c * 16 + j * 4 + rsel;
            const int idx = (p < cnt) ? list_s[p] : (int)lo;
            *(uint4*)&Ds[wave][j * 4 + rsel][chunk * 8] =
                *(const uint4*)(tab + (size_t)idx * 128 + chunk * 8);
        }
        floatx4 acc = {0.0f, 0.0f, 0.0f, 0.0f};
#pragma unroll
        for (int cc = 0; cc < 4; ++cc) {
            half8 bf = *(const half8*)&Ds[wave][col][cc * 32 + quad * 8];
            acc = __builtin_amdgcn_mfma_f32_16x16x32_f16(afrag[cc], bf, acc, 0, 0, 0);
        }
        if (c * 16 + col < cnt) {
#pragma unroll
            for (int r = 0; r < 4; ++r) {
                const float sim = acc[r];
#pragma unroll
                for (int k = 0; k < 11; ++k) {
                    const float tt = sim - (-1.0f + 0.2f * (float)k);
                    pr[r][k] += __builtin_amdgcn_exp2f(tt * tt * -72.13475204444817f);
                }
            }
        }
    }
#pragma unroll
    for (int r = 0; r < 4; ++r)
#pragma unroll
        for (int k = 0; k < 11; ++k)
            atomicAdd(&pooled_s[(quad * 4 + r) * 11 + k], pr[r][k]);
    __syncthreads();
    if (tid < 176) atomicAdd(&pooled[b * 176 + tid], pooled_s[tid]);
}

__global__ __launch_bounds__(256) void knrm_final_fb(
    const float* __restrict__ pooled, const float* __restrict__ W,
    const float* __restrict__ bias, float* __restrict__ out)
{
    const int tid   = threadIdx.x;
    const int lane  = tid & 63;
    const int batch = blockIdx.x * 4 + (tid >> 6);
    const float* pb = pooled + (size_t)batch * 176;
    float acc = 0.0f;
#pragma unroll
    for (int i = 0; i < 3; ++i) {
        const int f = lane + i * 64;
        if (f < 176)
            acc += __builtin_amdgcn_logf(pb[f]) * W[f % 11];
    }
    acc += __shfl_xor(acc, 1);  acc += __shfl_xor(acc, 2);
    acc += __shfl_xor(acc, 4);  acc += __shfl_xor(acc, 8);
    acc += __shfl_xor(acc, 16); acc += __shfl_xor(acc, 32);
    if (lane == 0) {
        const float t = acc * 0.69314718055994531f + bias[0];
        out[batch] = __builtin_amdgcn_rcpf(1.0f + __builtin_amdgcn_exp2f(t * -1.4426950408889634f));
    }
}

extern "C" void kernel_launch(void* const* d_in, const int* in_sizes, int n_in,
                              void* d_out, int out_size, void* d_ws, size_t ws_size,
                              hipStream_t stream) {
    const int*   queries   = (const int*)d_in[0];
    const int*   documents = (const int*)d_in[1];
    const float* emb       = (const float*)d_in[2];
    const float* W         = (const float*)d_in[3];
    const float* bias      = (const float*)d_in[4];
    float* out = (float*)d_out;
    char*  ws  = (char*)d_ws;

    _Float16* tab    = (_Float16*)(ws + TAB_OFF);
    float*    pooled = (float*)(ws + POOL_OFF);

    bool done = false;
    if (ws_size >= (size_t)WS_NEEDED) {
        void* args[] = {(void*)&queries, (void*)&documents, (void*)&emb, (void*)&W,
                        (void*)&bias, (void*)&tab, (void*)&pooled, (void*)&out};
        hipError_t e = hipLaunchCooperativeKernel((const void*)knrm_fused,
                                                  dim3(1024), dim3(256), args, 0, stream);
        done = (e == hipSuccess);
    }
    if (!done && ws_size >= (size_t)(WS_NEEDED + 524288)) {
        // non-cooperative fallback (needs qtab scratch after pooled)
        _Float16* qtab = (_Float16*)(ws + POOL_OFF + 90112);
        knrm_prep_fb<<<2176, 256, 0, stream>>>(emb, queries, tab, qtab, pooled);
        knrm_main_fb<<<1024, 256, 0, stream>>>(documents, tab, qtab, pooled);
        knrm_final_fb<<<32, 256, 0, stream>>>(pooled, W, bias, out);
    }
}